// Round 1
// baseline (181.543 us; speedup 1.0000x reference)
//
#include <hip/hip_runtime.h>
#include <stdint.h>

typedef unsigned short u16;
typedef __attribute__((ext_vector_type(8))) short short8;
typedef __attribute__((ext_vector_type(4))) float f32x4;
typedef __attribute__((ext_vector_type(8))) __bf16 bf16x8;

#define DEV static __device__ __forceinline__

// ---- bf16 MFMA with operand-type hedge (builtin may want short8 or bf16x8) ----
template <typename T>
DEV auto mfma_try(T a, T b, f32x4 c, int)
    -> decltype(__builtin_amdgcn_mfma_f32_16x16x32_bf16(a, b, c, 0, 0, 0)) {
  return __builtin_amdgcn_mfma_f32_16x16x32_bf16(a, b, c, 0, 0, 0);
}
template <typename T>
DEV f32x4 mfma_try(T a, T b, f32x4 c, long) {
  return __builtin_amdgcn_mfma_f32_16x16x32_bf16(
      __builtin_bit_cast(bf16x8, a), __builtin_bit_cast(bf16x8, b), c, 0, 0, 0);
}
DEV f32x4 MFMA(short8 a, short8 b, f32x4 c) { return mfma_try(a, b, c, 0); }

DEV void gload16(const u16* g, u16* lds) {
  __builtin_amdgcn_global_load_lds((unsigned int*)g, (unsigned int*)lds, 16, 0, 0);
}

DEV u16 f2bf(float f) {
  unsigned u = __float_as_uint(f);
  u = (u + 0x7FFFu + ((u >> 16) & 1u)) >> 16;
  return (u16)u;
}

// ---------------- fp32 -> bf16 conversion for x, Wqkv, Wo ----------------
__global__ void cvt_kernel(const float* __restrict__ x, const float* __restrict__ wq,
                           const float* __restrict__ wo, u16* __restrict__ xb,
                           u16* __restrict__ wqb, u16* __restrict__ wob) {
  const int N1 = 4194304 / 4, N2 = 3145728 / 4, N3 = 1048576 / 4;
  const int total = N1 + N2 + N3;
  for (int i = blockIdx.x * blockDim.x + threadIdx.x; i < total;
       i += gridDim.x * blockDim.x) {
    const float4* s;
    u16* d;
    int off;
    if (i < N1) { s = (const float4*)x; d = xb; off = i; }
    else if (i < N1 + N2) { s = (const float4*)wq; d = wqb; off = i - N1; }
    else { s = (const float4*)wo; d = wob; off = i - N1 - N2; }
    float4 v = s[off];
    ushort4 o;
    o.x = f2bf(v.x); o.y = f2bf(v.y); o.z = f2bf(v.z); o.w = f2bf(v.w);
    ((ushort4*)d)[off] = o;
  }
}

// ---------------- GEMM: C = A * B^T + bias  (A: MxK bf16, B: NxK bf16) ----------------
// EPI==0: scatter to Q/K/VT with the "faithful reshape" index map (GEMM1, N=3072)
// EPI==1: fp32 output + bias (GEMM2)
template <int EPI>
__global__ __launch_bounds__(256, 2) void gemm_bt(
    const u16* __restrict__ A, const u16* __restrict__ Bm,
    const float* __restrict__ bias, float* __restrict__ Cf,
    u16* __restrict__ Qb, u16* __restrict__ Kb, u16* __restrict__ VTb,
    int M, int N, int K) {
  __shared__ u16 As[128 * 32];
  __shared__ u16 Bs[128 * 32];
  const int tid = threadIdx.x;
  const int lane = tid & 63;
  const int wave = tid >> 6;
  const int wr = wave >> 1, wc = wave & 1;
  const int l15 = lane & 15, l4 = lane >> 4;
  const int m0 = blockIdx.y * 128, n0 = blockIdx.x * 128;

  f32x4 acc[4][4] = {};

  const u16* ga = A + (size_t)(m0 + (tid >> 2)) * K + (tid & 3) * 8;
  const u16* gb = Bm + (size_t)(n0 + (tid >> 2)) * K + (tid & 3) * 8;
  u16* la = As + tid * 8;
  u16* lb = Bs + tid * 8;
  const size_t rstep = (size_t)64 * K;

  for (int kt = 0; kt < K; kt += 32) {
    gload16(ga + kt, la);
    gload16(ga + kt + rstep, la + 2048);
    gload16(gb + kt, lb);
    gload16(gb + kt + rstep, lb + 2048);
    __syncthreads();
    short8 af[4], bfr[4];
#pragma unroll
    for (int i = 0; i < 4; ++i)
      af[i] = *(const short8*)(As + (wr * 64 + i * 16 + l15) * 32 + l4 * 8);
#pragma unroll
    for (int i = 0; i < 4; ++i)
      bfr[i] = *(const short8*)(Bs + (wc * 64 + i * 16 + l15) * 32 + l4 * 8);
#pragma unroll
    for (int i = 0; i < 4; ++i)
#pragma unroll
      for (int j = 0; j < 4; ++j) acc[i][j] = MFMA(af[i], bfr[j], acc[i][j]);
    __syncthreads();
  }

  if constexpr (EPI == 0) {
#pragma unroll
    for (int nj = 0; nj < 4; ++nj) {
      const int c = n0 + wc * 64 + nj * 16 + l15;
      const float bv = bias[c];
      const int chunk = c / 192;
      const int t = c - chunk * 192;
      const int sel = t >> 6;
      const int dd = t & 63;
#pragma unroll
      for (int mi = 0; mi < 4; ++mi) {
#pragma unroll
        for (int r = 0; r < 4; ++r) {
          const int m = m0 + wr * 64 + mi * 16 + l4 * 4 + r;
          const u16 bfv = f2bf(acc[mi][nj][r] + bv);
          const int bb = m >> 11;
          const int s = m & 2047;
          const int hhh = s >> 7;
          const int rr = s & 127;
          const int s2 = rr * 16 + chunk;
          const int bh = bb * 16 + hhh;
          if (sel == 0)
            Qb[((size_t)bh * 2048 + s2) * 64 + dd] = bfv;
          else if (sel == 1)
            Kb[((size_t)bh * 2048 + s2) * 64 + dd] = bfv;
          else
            VTb[((size_t)bh * 64 + dd) * 2048 + s2] = bfv;
        }
      }
    }
  } else {
#pragma unroll
    for (int nj = 0; nj < 4; ++nj) {
      const int c = n0 + wc * 64 + nj * 16 + l15;
      const float bv = bias[c];
#pragma unroll
      for (int mi = 0; mi < 4; ++mi) {
#pragma unroll
        for (int r = 0; r < 4; ++r) {
          const int m = m0 + wr * 64 + mi * 16 + l4 * 4 + r;
          Cf[(size_t)m * N + c] = acc[mi][nj][r] + bv;
        }
      }
    }
  }
}

// ---------------- flash attention over 32 (b,h) problems of 2048 x hd=64 ----------------
// Q,K: [bh][2048][64] bf16 ; VT: [bh][64][2048] bf16 ; out v2: [4096][1024] bf16
__global__ __launch_bounds__(256, 2) void attn_kernel(
    const u16* __restrict__ Qg, const u16* __restrict__ Kg,
    const u16* __restrict__ VTg, u16* __restrict__ v2) {
  __shared__ u16 Ks[128 * 64];       // 16KB, block-swizzled
  __shared__ u16 VTs[64 * 128];      // 16KB, block-swizzled
  __shared__ u16 Ps[4][32 * 128];    // 32KB, per-wave P tiles, swizzled

  const int tid = threadIdx.x;
  const int lane = tid & 63;
  const int wave = tid >> 6;
  const int l15 = lane & 15, l4 = lane >> 4;
  const int bh = blockIdx.x >> 4;
  const int qt = blockIdx.x & 15;
  const int bb = bh >> 4, hh = bh & 15;

  const u16* Qh = Qg + (size_t)bh * 2048 * 64;
  const u16* Kh = Kg + (size_t)bh * 2048 * 64;
  const u16* VTh = VTg + (size_t)bh * 64 * 2048;

  const int q0 = qt * 128 + wave * 32;

  short8 qf[2][2];
#pragma unroll
  for (int mi = 0; mi < 2; ++mi)
#pragma unroll
    for (int ks = 0; ks < 2; ++ks)
      qf[mi][ks] =
          *(const short8*)(Qh + (size_t)(q0 + mi * 16 + l15) * 64 + ks * 32 + l4 * 8);

  f32x4 o[2][4] = {};
  float mrun[2][4], lrun[2][4];
#pragma unroll
  for (int mi = 0; mi < 2; ++mi)
#pragma unroll
    for (int r = 0; r < 4; ++r) { mrun[mi][r] = -1e30f; lrun[mi][r] = 0.f; }

  u16* Pw = &Ps[wave][0];

  for (int t = 0; t < 16; ++t) {
    const int kv0 = t * 128;
    // stage K tile [128 rows][64], source-permuted so LDS[r][g] = K[r][g ^ (r&7)]
#pragma unroll
    for (int i = 0; i < 4; ++i) {
      const int r = (tid >> 3) + i * 32;
      const int gblk = (tid & 7) ^ (r & 7);
      gload16(Kh + (size_t)(kv0 + r) * 64 + gblk * 8, Ks + tid * 8 + i * 2048);
    }
    // stage VT tile [64 rows][128], LDS[d][g] = VT[d][g ^ (d&7)]
#pragma unroll
    for (int i = 0; i < 4; ++i) {
      const int d = (tid >> 4) + i * 16;
      const int gblk = (tid & 15) ^ (d & 7);
      gload16(VTh + (size_t)d * 2048 + kv0 + gblk * 8, VTs + tid * 8 + i * 2048);
    }
    __syncthreads();

    // S = Q K^T (scale folded into softmax)
    f32x4 sacc[2][8] = {};
#pragma unroll
    for (int ks = 0; ks < 2; ++ks) {
#pragma unroll
      for (int ni = 0; ni < 8; ++ni) {
        const int row = ni * 16 + l15;
        short8 kf =
            *(const short8*)(Ks + row * 64 + ((ks * 4 + l4) ^ (row & 7)) * 8);
        sacc[0][ni] = MFMA(qf[0][ks], kf, sacc[0][ni]);
        sacc[1][ni] = MFMA(qf[1][ks], kf, sacc[1][ni]);
      }
    }

    // online softmax: row max (in-lane over ni, then 16-lane shfl tree)
    float rm[2][4];
#pragma unroll
    for (int mi = 0; mi < 2; ++mi)
#pragma unroll
      for (int r = 0; r < 4; ++r) {
        float v = sacc[mi][0][r];
#pragma unroll
        for (int ni = 1; ni < 8; ++ni) v = fmaxf(v, sacc[mi][ni][r]);
        rm[mi][r] = v * 0.125f;
      }
#pragma unroll
    for (int off = 1; off < 16; off <<= 1)
#pragma unroll
      for (int mi = 0; mi < 2; ++mi)
#pragma unroll
        for (int r = 0; r < 4; ++r)
          rm[mi][r] = fmaxf(rm[mi][r], __shfl_xor(rm[mi][r], off));

    float scl[2][4], rs[2][4];
#pragma unroll
    for (int mi = 0; mi < 2; ++mi)
#pragma unroll
      for (int r = 0; r < 4; ++r) {
        const float mn = fmaxf(mrun[mi][r], rm[mi][r]);
        scl[mi][r] = __expf(mrun[mi][r] - mn);
        mrun[mi][r] = mn;
        rs[mi][r] = 0.f;
      }

    // P = exp(0.125*S - m): accumulate row sums, write bf16 P to per-wave LDS (swizzled)
#pragma unroll
    for (int mi = 0; mi < 2; ++mi)
#pragma unroll
      for (int ni = 0; ni < 8; ++ni)
#pragma unroll
        for (int r = 0; r < 4; ++r) {
          const float p = __expf(fmaf(sacc[mi][ni][r], 0.125f, -mrun[mi][r]));
          rs[mi][r] += p;
          const int row = mi * 16 + l4 * 4 + r;
          const int col = ni * 16 + l15;
          Pw[row * 128 + (col ^ ((row & 7) << 3))] = f2bf(p);
        }

#pragma unroll
    for (int off = 1; off < 16; off <<= 1)
#pragma unroll
      for (int mi = 0; mi < 2; ++mi)
#pragma unroll
        for (int r = 0; r < 4; ++r) rs[mi][r] += __shfl_xor(rs[mi][r], off);

#pragma unroll
    for (int mi = 0; mi < 2; ++mi)
#pragma unroll
      for (int r = 0; r < 4; ++r) lrun[mi][r] = lrun[mi][r] * scl[mi][r] + rs[mi][r];

#pragma unroll
    for (int mi = 0; mi < 2; ++mi)
#pragma unroll
      for (int di = 0; di < 4; ++di)
#pragma unroll
        for (int r = 0; r < 4; ++r) o[mi][di][r] *= scl[mi][r];

    // O += P * V   (A-frags from Pw, B-frags from VTs, both swizzle-matched)
#pragma unroll
    for (int ks = 0; ks < 4; ++ks) {
      short8 pa[2];
#pragma unroll
      for (int mi = 0; mi < 2; ++mi) {
        const int row = mi * 16 + l15;
        pa[mi] = *(const short8*)(Pw + row * 128 +
                                  ((ks * 32 + l4 * 8) ^ ((row & 7) << 3)));
      }
#pragma unroll
      for (int di = 0; di < 4; ++di) {
        const int d = di * 16 + l15;
        short8 vb = *(const short8*)(VTs + d * 128 +
                                     ((ks * 32 + l4 * 8) ^ ((d & 7) << 3)));
        o[0][di] = MFMA(pa[0], vb, o[0][di]);
        o[1][di] = MFMA(pa[1], vb, o[1][di]);
      }
    }
    __syncthreads();
  }

  // normalize + scatter through the inverse "faithful reshape"
#pragma unroll
  for (int mi = 0; mi < 2; ++mi)
#pragma unroll
    for (int r = 0; r < 4; ++r) {
      const float inv = 1.0f / lrun[mi][r];
      const int s2 = q0 + mi * 16 + l4 * 4 + r;
      const int rowO = bb * 2048 + hh * 128 + (s2 >> 4);
      const int colbase = (s2 & 15) * 64;
#pragma unroll
      for (int di = 0; di < 4; ++di)
        v2[(size_t)rowO * 1024 + colbase + di * 16 + l15] =
            f2bf(o[mi][di][r] * inv);
    }
}

extern "C" void kernel_launch(void* const* d_in, const int* in_sizes, int n_in,
                              void* d_out, int out_size, void* d_ws, size_t ws_size,
                              hipStream_t stream) {
  const float* x = (const float*)d_in[0];
  const float* Wqkv = (const float*)d_in[1];
  const float* bqkv = (const float*)d_in[2];
  const float* Wo = (const float*)d_in[3];
  const float* bo = (const float*)d_in[4];
  float* out = (float*)d_out;

  char* ws = (char*)d_ws;
  u16* xb  = (u16*)(ws);                  // 4096*1024*2  = 8 MB
  u16* wqb = (u16*)(ws + 8388608);        // 3072*1024*2  = 6 MB
  u16* wob = (u16*)(ws + 14680064);       // 1024*1024*2  = 2 MB
  u16* Qb  = (u16*)(ws + 16777216);       // 32*2048*64*2 = 8 MB
  u16* Kb  = (u16*)(ws + 25165824);       // 8 MB
  u16* VTb = (u16*)(ws + 33554432);       // 8 MB  [bh][64][2048]
  u16* v2  = (u16*)(ws + 41943040);       // 4096*1024*2  = 8 MB

  cvt_kernel<<<2048, 256, 0, stream>>>(x, Wqkv, Wo, xb, wqb, wob);

  dim3 g1(24, 32);  // N/128, M/128
  gemm_bt<0><<<g1, 256, 0, stream>>>(xb, wqb, bqkv, nullptr, Qb, Kb, VTb,
                                     4096, 3072, 1024);

  attn_kernel<<<512, 256, 0, stream>>>(Qb, Kb, VTb, v2);

  dim3 g2(8, 32);
  gemm_bt<1><<<g2, 256, 0, stream>>>(v2, wob, bo, out, nullptr, nullptr, nullptr,
                                     4096, 1024, 1024);
}